// Round 9
// baseline (168.816 us; speedup 1.0000x reference)
//
#include <hip/hip_runtime.h>

#define N_NODES 8192
#define IN_F    1024
#define OUT_F   512
#define N_EDGES 262144
#define STRIDE  96                // fixed adjacency row stride; P(deg>=96) ~ 1e-18
#define NBLK    32                // histogram blocks: 32 x 8192 edges

// ---------------- workspace layout (bytes) ----------------
#define HID_OFF     0u            // 8192*512*2  = 8,388,608  (bf16 H)
#define WB_OFF      8388608u      // 512*1024*2  = 1,048,576  (bf16 W)
#define DEG_OFF     9437184u      // 8192*4 = 32,768
#define COL_OFF     9469952u      // 8192*96*4 = 3,145,728
#define BH_OFF      12615680u     // 32*8192*4 = 1,048,576   (blkhist)
#define BO_OFF      13664256u     // 32*8192*4 = 1,048,576   (boff) -> ends 14,712,832
#define MAX_DEG     STRIDE

typedef short  bf16x8 __attribute__((ext_vector_type(8)));
typedef float  f32x4  __attribute__((ext_vector_type(4)));

__device__ __forceinline__ unsigned f2bf(float f) {
    unsigned u = __float_as_uint(f);
    u += 0x7fffu + ((u >> 16) & 1u);   // round-to-nearest-even
    return u >> 16;
}

__device__ __forceinline__ float bflo(unsigned u) { return __uint_as_float(u << 16); }
__device__ __forceinline__ float bfhi(unsigned u) { return __uint_as_float(u & 0xffff0000u); }

__device__ __forceinline__ void ld_lds16(const void* g, void* l) {
    __builtin_amdgcn_global_load_lds(
        (const __attribute__((address_space(1))) void*)g,
        (__attribute__((address_space(3))) void*)l, 16, 0, 0);
}

// --- prep: W fp32 -> bf16 (1 MB). 65536 threads ---
#define NW8 (OUT_F * IN_F / 8)            // 65,536 chunks of 8
__global__ __launch_bounds__(256) void prep(const float* __restrict__ w,
                                            unsigned short* __restrict__ wb) {
    int i = blockIdx.x * blockDim.x + threadIdx.x;
    const f32x4* p = (const f32x4*)w + (size_t)i * 2;
    f32x4 v0 = __builtin_nontemporal_load(p);
    f32x4 v1 = __builtin_nontemporal_load(p + 1);
    uint4 o;
    o.x = f2bf(v0.x) | (f2bf(v0.y) << 16);
    o.y = f2bf(v0.z) | (f2bf(v0.w) << 16);
    o.z = f2bf(v1.x) | (f2bf(v1.y) << 16);
    o.w = f2bf(v1.z) | (f2bf(v1.w) << 16);
    *((uint4*)wb + i) = o;
}

// --- histA: per-block LDS histogram of src over 8192 bins, no global atomics ---
__global__ __launch_bounds__(256) void hist_a(const int* __restrict__ src,
                                              int* __restrict__ blkhist) {
    __shared__ int h[N_NODES];            // 32 KB
    const int b   = blockIdx.x;
    const int tid = threadIdx.x;
    for (int i = tid; i < N_NODES; i += 256) h[i] = 0;
    __syncthreads();
    const int e0 = b * (N_EDGES / NBLK);
#pragma unroll
    for (int j = 0; j < N_EDGES / NBLK / 256; ++j)
        atomicAdd(&h[src[e0 + j * 256 + tid]], 1);
    __syncthreads();
    for (int i = tid; i < N_NODES; i += 256)
        blkhist[b * N_NODES + i] = h[i];
}

// --- scanB: per node, prefix over 32 block counts -> local boff + deg ---
__global__ __launch_bounds__(256) void scan_b(const int* __restrict__ blkhist,
                                              int* __restrict__ boff,
                                              int* __restrict__ deg) {
    const int i = blockIdx.x * 256 + threadIdx.x;   // node id, grid 32x256 = 8192
    int s = 0;
#pragma unroll
    for (int b = 0; b < NBLK; ++b) {
        int t = blkhist[b * N_NODES + i];           // coalesced across threads
        boff[b * N_NODES + i] = s;                  // local (within-row) offset
        s += t;
    }
    deg[i] = s;
}

// --- placeC: recompute local rank via LDS histogram, write col. No global atomics ---
__global__ __launch_bounds__(256) void place_c(const int* __restrict__ src,
                                               const int* __restrict__ dst,
                                               const int* __restrict__ boff,
                                               int* __restrict__ col) {
    __shared__ int h[N_NODES];            // 32 KB
    const int b   = blockIdx.x;
    const int tid = threadIdx.x;
    for (int i = tid; i < N_NODES; i += 256) h[i] = 0;
    __syncthreads();
    const int e0 = b * (N_EDGES / NBLK);
#pragma unroll
    for (int j = 0; j < N_EDGES / NBLK / 256; ++j) {
        int e = e0 + j * 256 + tid;
        int s = src[e];
        int r = boff[b * N_NODES + s] + atomicAdd(&h[s], 1);
        if (r < STRIDE) col[s * STRIDE + r] = dst[e];
    }
}

// ---------------- MFMA GEMM: H = bf16(X @ W^T + b), solo ----------------
// 64x64 tile, BK=64 (16 iters), 4 waves (2x2), each wave 2x2 of 16x16x32.
// A-path: X fp32 global->reg, f2bf in-reg, ds_write_b128 into swizzled LDS.
// B-path: bf16 W via global_load_lds (lane-pinned, swizzled fetch).
// LDS chunk (row, kc) at slot kc^(row&7) -> conflict-free fragment reads.
__global__ __launch_bounds__(256, 6) void gemm_mfma(const float* __restrict__ X,
                                                    const unsigned short* __restrict__ Wb,
                                                    const float* __restrict__ bias,
                                                    unsigned short* __restrict__ H) {
    __shared__ unsigned short As[64 * 64];   // 8 KB
    __shared__ unsigned short Bs[64 * 64];   // 8 KB

    const int bid  = blockIdx.x;
    const int tid  = threadIdx.x;
    const int lane = tid & 63;
    const int wave = tid >> 6;
    const int row0 = (bid & 127) * 64;       // 128 row-tiles; bid%8 groups by XCD
    const int col0 = (bid >> 7) * 64;        // 8 col-tiles
    const int wm   = (wave & 1) * 32;
    const int wn   = (wave >> 1) * 32;
    const int fm   = lane & 15;
    const int fm7  = fm & 7;
    const int q    = lane >> 4;

    f32x4 acc[2][2];
#pragma unroll
    for (int i = 0; i < 2; ++i)
#pragma unroll
        for (int j = 0; j < 2; ++j) acc[i][j] = (f32x4)0.f;

    const int ar   = tid >> 2;                       // 0..63
    const int ak4  = tid & 3;                        // 0..3
    const int ar7  = ar & 7;
    unsigned short* As_w0 = As + ar * 64 + ((ak4 * 2)     ^ ar7) * 8;
    unsigned short* As_w1 = As + ar * 64 + ((ak4 * 2 + 1) ^ ar7) * 8;
    const float* xrow = &X[(size_t)(row0 + ar) * IN_F + ak4 * 16];

    const int br = tid >> 3;                         // 0..31
    const int bk = ((tid & 7) ^ (br & 7)) * 8;

    for (int k0 = 0; k0 < IN_F; k0 += 64) {
        const f32x4* px = (const f32x4*)(xrow + k0);
        f32x4 v0 = px[0], v1 = px[1], v2 = px[2], v3 = px[3];
        ld_lds16(Wb + (size_t)(col0 + br) * IN_F + k0 + bk,      Bs + tid * 8);
        ld_lds16(Wb + (size_t)(col0 + br + 32) * IN_F + k0 + bk, Bs + (tid + 256) * 8);
        uint4 pa, pb;
        pa.x = f2bf(v0.x) | (f2bf(v0.y) << 16);
        pa.y = f2bf(v0.z) | (f2bf(v0.w) << 16);
        pa.z = f2bf(v1.x) | (f2bf(v1.y) << 16);
        pa.w = f2bf(v1.z) | (f2bf(v1.w) << 16);
        pb.x = f2bf(v2.x) | (f2bf(v2.y) << 16);
        pb.y = f2bf(v2.z) | (f2bf(v2.w) << 16);
        pb.z = f2bf(v3.x) | (f2bf(v3.y) << 16);
        pb.w = f2bf(v3.z) | (f2bf(v3.w) << 16);
        *(uint4*)As_w0 = pa;
        *(uint4*)As_w1 = pb;
        __syncthreads();

#pragma unroll
        for (int s = 0; s < 2; ++s) {
            const int kq = s * 4 + q;
            bf16x8 a[2], b[2];
#pragma unroll
            for (int mi = 0; mi < 2; ++mi)
                a[mi] = *(const bf16x8*)&As[(((wm + mi * 16 + fm) << 3) + (kq ^ fm7)) << 3];
#pragma unroll
            for (int ni = 0; ni < 2; ++ni)
                b[ni] = *(const bf16x8*)&Bs[(((wn + ni * 16 + fm) << 3) + (kq ^ fm7)) << 3];
#pragma unroll
            for (int mi = 0; mi < 2; ++mi)
#pragma unroll
                for (int ni = 0; ni < 2; ++ni)
                    acc[mi][ni] = __builtin_amdgcn_mfma_f32_16x16x32_bf16(
                        a[mi], b[ni], acc[mi][ni], 0, 0, 0);
        }
        __syncthreads();
    }

    const int cm = (lane >> 4) * 4;   // C/D: col = lane&15, row = (lane>>4)*4 + reg
#pragma unroll
    for (int ni = 0; ni < 2; ++ni) {
        const int c = col0 + wn + ni * 16 + fm;
        const float bv = bias[c];
#pragma unroll
        for (int mi = 0; mi < 2; ++mi) {
#pragma unroll
            for (int r = 0; r < 4; ++r) {
                const int row = row0 + wm + mi * 16 + cm + r;
                H[(size_t)row * OUT_F + c] = (unsigned short)f2bf(acc[mi][ni][r] + bv);
            }
        }
    }
}

// ---- aggregate: wave-per-node. 64 lanes x 8 feats = 512. No block barriers. ----
__global__ __launch_bounds__(256) void aggregate(const unsigned short* __restrict__ H,
                                                 const int* __restrict__ dg,
                                                 const int* __restrict__ col,
                                                 float* __restrict__ out) {
    __shared__ int nbr[4][MAX_DEG];
    __shared__ int uniq[4][MAX_DEG];
    __shared__ int wcnt[4];
    const int wave = threadIdx.x >> 6;
    const int lane = threadIdx.x & 63;
    const int v    = blockIdx.x * 4 + wave;
    int d = dg[v];
    if (d > MAX_DEG) d = MAX_DEG;

    if (lane == 0) wcnt[wave] = 0;
    int id0 = -1, id1 = -1;
    if (lane < d)      { id0 = col[v * STRIDE + lane];      nbr[wave][lane]      = id0; }
    if (64 + lane < d) { id1 = col[v * STRIDE + 64 + lane]; nbr[wave][64 + lane] = id1; }
    __builtin_amdgcn_wave_barrier();

    bool k0 = (lane < d);
    const int lim0 = k0 ? lane : 0;
    for (int j = 0; j < lim0; ++j) k0 = k0 & (nbr[wave][j] != id0);
    bool k1 = (64 + lane < d);
    const int lim1 = k1 ? (64 + lane) : 0;
    for (int j = 0; j < lim1; ++j) k1 = k1 & (nbr[wave][j] != id1);
    if (k0) uniq[wave][atomicAdd(&wcnt[wave], 1)] = id0;
    if (k1) uniq[wave][atomicAdd(&wcnt[wave], 1)] = id1;
    __builtin_amdgcn_wave_barrier();
    const int n  = wcnt[wave];
    const int f0 = lane * 8;

    float a0=0,a1=0,a2=0,a3=0,a4=0,a5=0,a6=0,a7=0;
    int e = 0;
    for (; e + 4 <= n; e += 4) {
        const int i0 = uniq[wave][e], i1 = uniq[wave][e+1],
                  i2 = uniq[wave][e+2], i3 = uniq[wave][e+3];
        uint4 h0 = *(const uint4*)&H[(size_t)i0 * OUT_F + f0];
        uint4 h1 = *(const uint4*)&H[(size_t)i1 * OUT_F + f0];
        uint4 h2 = *(const uint4*)&H[(size_t)i2 * OUT_F + f0];
        uint4 h3 = *(const uint4*)&H[(size_t)i3 * OUT_F + f0];
        a0 += bflo(h0.x)+bflo(h1.x)+bflo(h2.x)+bflo(h3.x);
        a1 += bfhi(h0.x)+bfhi(h1.x)+bfhi(h2.x)+bfhi(h3.x);
        a2 += bflo(h0.y)+bflo(h1.y)+bflo(h2.y)+bflo(h3.y);
        a3 += bfhi(h0.y)+bfhi(h1.y)+bfhi(h2.y)+bfhi(h3.y);
        a4 += bflo(h0.z)+bflo(h1.z)+bflo(h2.z)+bflo(h3.z);
        a5 += bfhi(h0.z)+bfhi(h1.z)+bfhi(h2.z)+bfhi(h3.z);
        a6 += bflo(h0.w)+bflo(h1.w)+bflo(h2.w)+bflo(h3.w);
        a7 += bfhi(h0.w)+bfhi(h1.w)+bfhi(h2.w)+bfhi(h3.w);
    }
    for (; e < n; ++e) {
        uint4 h0 = *(const uint4*)&H[(size_t)uniq[wave][e] * OUT_F + f0];
        a0 += bflo(h0.x); a1 += bfhi(h0.x);
        a2 += bflo(h0.y); a3 += bfhi(h0.y);
        a4 += bflo(h0.z); a5 += bfhi(h0.z);
        a6 += bflo(h0.w); a7 += bfhi(h0.w);
    }
    f32x4 o0 = {fmaxf(a0,0.f), fmaxf(a1,0.f), fmaxf(a2,0.f), fmaxf(a3,0.f)};
    f32x4 o1 = {fmaxf(a4,0.f), fmaxf(a5,0.f), fmaxf(a6,0.f), fmaxf(a7,0.f)};
    __builtin_nontemporal_store(o0, (f32x4*)&out[(size_t)v * OUT_F + f0]);
    __builtin_nontemporal_store(o1, (f32x4*)&out[(size_t)v * OUT_F + f0 + 4]);
}

extern "C" void kernel_launch(void* const* d_in, const int* in_sizes, int n_in,
                              void* d_out, int out_size, void* d_ws, size_t ws_size,
                              hipStream_t stream) {
    const float* x  = (const float*)d_in[0];
    const float* W  = (const float*)d_in[1];
    const float* b  = (const float*)d_in[2];
    const int*   ei = (const int*)d_in[3];      // [2, N_EDGES]: src then dst
    float* out = (float*)d_out;

    char* ws = (char*)d_ws;
    unsigned short* H       = (unsigned short*)(ws + HID_OFF);
    unsigned short* Wb      = (unsigned short*)(ws + WB_OFF);
    int*            deg     = (int*)(ws + DEG_OFF);
    int*            col     = (int*)(ws + COL_OFF);
    int*            blkhist = (int*)(ws + BH_OFF);
    int*            boff    = (int*)(ws + BO_OFF);

    const int* src = ei;
    const int* dst = ei + N_EDGES;

    prep<<<NW8 / 256, 256, 0, stream>>>(W, Wb);
    hist_a<<<NBLK, 256, 0, stream>>>(src, blkhist);
    scan_b<<<N_NODES / 256, 256, 0, stream>>>(blkhist, boff, deg);
    place_c<<<NBLK, 256, 0, stream>>>(src, dst, boff, col);
    gemm_mfma<<<1024, 256, 0, stream>>>(x, Wb, b, H);
    aggregate<<<N_NODES / 4, 256, 0, stream>>>(H, deg, col, out);
}

// Round 10
// 153.142 us; speedup vs baseline: 1.1023x; 1.1023x over previous
//
#include <hip/hip_runtime.h>

#define N_NODES 8192
#define IN_F    1024
#define OUT_F   512
#define N_EDGES 262144
#define STRIDE  96                // fixed adjacency row stride; P(deg>=96) ~ 1e-18
#define NBLK    64                // counting-sort blocks: 64 x 4096 edges
#define EPB     (N_EDGES / NBLK)  // 4096 edges per block

// ---------------- workspace layout (bytes) ----------------
#define HID_OFF     0u            // 8192*512*2  = 8,388,608  (bf16 H)
#define WB_OFF      8388608u      // 512*1024*2  = 1,048,576  (bf16 W)
#define DEG_OFF     9437184u      // 8192*4 = 32,768
#define COL_OFF     9469952u      // 8192*96*4 = 3,145,728
#define BH_OFF      12615680u     // 64*8192*4 = 2,097,152   (blkhist)
#define BO_OFF      14712832u     // 64*8192*4 = 2,097,152   (boff) -> ends 16,809,984
#define MAX_DEG     STRIDE

typedef short  bf16x8 __attribute__((ext_vector_type(8)));
typedef float  f32x4  __attribute__((ext_vector_type(4)));

__device__ __forceinline__ unsigned f2bf(float f) {
    unsigned u = __float_as_uint(f);
    u += 0x7fffu + ((u >> 16) & 1u);   // round-to-nearest-even
    return u >> 16;
}

__device__ __forceinline__ float bflo(unsigned u) { return __uint_as_float(u << 16); }
__device__ __forceinline__ float bfhi(unsigned u) { return __uint_as_float(u & 0xffff0000u); }

__device__ __forceinline__ void ld_lds16(const void* g, void* l) {
    __builtin_amdgcn_global_load_lds(
        (const __attribute__((address_space(1))) void*)g,
        (__attribute__((address_space(3))) void*)l, 16, 0, 0);
}

// --- fused: W fp32->bf16 (blocks 0..255) + per-block src histogram (256..319) ---
#define NW8 (OUT_F * IN_F / 8)            // 65,536 chunks of 8
__global__ __launch_bounds__(256) void prep_hist(const float* __restrict__ w,
                                                 unsigned short* __restrict__ wb,
                                                 const int* __restrict__ src,
                                                 int* __restrict__ blkhist) {
    __shared__ int h[N_NODES];            // 32 KB
    const int bid = blockIdx.x;
    const int tid = threadIdx.x;

    if (bid < 256) {                      // ---- W conversion ----
        int i = bid * 256 + tid;
        const f32x4* p = (const f32x4*)w + (size_t)i * 2;
        f32x4 v0 = __builtin_nontemporal_load(p);
        f32x4 v1 = __builtin_nontemporal_load(p + 1);
        uint4 o;
        o.x = f2bf(v0.x) | (f2bf(v0.y) << 16);
        o.y = f2bf(v0.z) | (f2bf(v0.w) << 16);
        o.z = f2bf(v1.x) | (f2bf(v1.y) << 16);
        o.w = f2bf(v1.z) | (f2bf(v1.w) << 16);
        *((uint4*)wb + i) = o;
        return;
    }
    // ---- histogram: block b over edges [b*EPB, (b+1)*EPB) ----
    const int b = bid - 256;
    for (int i = tid; i < N_NODES; i += 256) h[i] = 0;
    __syncthreads();
    const int e0 = b * EPB;
#pragma unroll
    for (int j = 0; j < EPB / 256; ++j)
        atomicAdd(&h[src[e0 + j * 256 + tid]], 1);
    __syncthreads();
    for (int i = tid; i < N_NODES; i += 256)
        blkhist[b * N_NODES + i] = h[i];
}

// --- scanB: per node, prefix over 64 block counts -> local boff + deg ---
__global__ __launch_bounds__(256) void scan_b(const int* __restrict__ blkhist,
                                              int* __restrict__ boff,
                                              int* __restrict__ deg) {
    const int i = blockIdx.x * 256 + threadIdx.x;   // node id, grid 32x256 = 8192
    int s = 0;
#pragma unroll 8
    for (int b = 0; b < NBLK; ++b) {
        int t = blkhist[b * N_NODES + i];           // coalesced across threads
        boff[b * N_NODES + i] = s;
        s += t;
    }
    deg[i] = s;
}

// ------ fused: MFMA GEMM (blocks 0..1023) + place pass (1024..1087) -------
// GEMM: 64x64 tile, BK=64, 4 waves (2x2), each wave 2x2 of 16x16x32.
//   A-path: X fp32 global->reg, f2bf in-reg, ds_write_b128 (swizzled LDS).
//   B-path: bf16 W via global_load_lds. Chunk (row,kc) at slot kc^(row&7).
// Place: recompute local rank via LDS histogram (no global atomics), write col.
//   Hidden under the GEMM. Shared-mem union = 32 KB.
__global__ __launch_bounds__(256, 4) void gemm_place(const float* __restrict__ X,
                                                     const unsigned short* __restrict__ Wb,
                                                     const float* __restrict__ bias,
                                                     unsigned short* __restrict__ H,
                                                     const int* __restrict__ src,
                                                     const int* __restrict__ dst,
                                                     const int* __restrict__ boff,
                                                     int* __restrict__ col) {
    __shared__ int smem[N_NODES];            // 32 KB union
    const int bid = blockIdx.x;
    const int tid = threadIdx.x;

    if (bid >= 1024) {                       // ---- place pass ----
        const int b = bid - 1024;
        for (int i = tid; i < N_NODES; i += 256) smem[i] = 0;
        __syncthreads();
        const int e0 = b * EPB;
#pragma unroll
        for (int j = 0; j < EPB / 256; ++j) {
            int e = e0 + j * 256 + tid;
            int s = src[e];
            int r = boff[b * N_NODES + s] + atomicAdd(&smem[s], 1);
            if (r < STRIDE) col[s * STRIDE + r] = dst[e];
        }
        return;
    }

    // ---- GEMM part ----
    unsigned short* As = (unsigned short*)smem;        // 8 KB
    unsigned short* Bs = (unsigned short*)smem + 4096; // 8 KB
    const int lane = tid & 63;
    const int wave = tid >> 6;
    const int row0 = (bid & 127) * 64;       // bid%8 groups row-tiles per XCD
    const int col0 = (bid >> 7) * 64;
    const int wm   = (wave & 1) * 32;
    const int wn   = (wave >> 1) * 32;
    const int fm   = lane & 15;
    const int fm7  = fm & 7;
    const int q    = lane >> 4;

    f32x4 acc[2][2];
#pragma unroll
    for (int i = 0; i < 2; ++i)
#pragma unroll
        for (int j = 0; j < 2; ++j) acc[i][j] = (f32x4)0.f;

    const int ar   = tid >> 2;                       // 0..63
    const int ak4  = tid & 3;                        // 0..3
    const int ar7  = ar & 7;
    unsigned short* As_w0 = As + ar * 64 + ((ak4 * 2)     ^ ar7) * 8;
    unsigned short* As_w1 = As + ar * 64 + ((ak4 * 2 + 1) ^ ar7) * 8;
    const float* xrow = &X[(size_t)(row0 + ar) * IN_F + ak4 * 16];

    const int br = tid >> 3;                         // 0..31
    const int bk = ((tid & 7) ^ (br & 7)) * 8;

    for (int k0 = 0; k0 < IN_F; k0 += 64) {
        const f32x4* px = (const f32x4*)(xrow + k0);
        f32x4 v0 = px[0], v1 = px[1], v2 = px[2], v3 = px[3];
        ld_lds16(Wb + (size_t)(col0 + br) * IN_F + k0 + bk,      Bs + tid * 8);
        ld_lds16(Wb + (size_t)(col0 + br + 32) * IN_F + k0 + bk, Bs + (tid + 256) * 8);
        uint4 pa, pb;
        pa.x = f2bf(v0.x) | (f2bf(v0.y) << 16);
        pa.y = f2bf(v0.z) | (f2bf(v0.w) << 16);
        pa.z = f2bf(v1.x) | (f2bf(v1.y) << 16);
        pa.w = f2bf(v1.z) | (f2bf(v1.w) << 16);
        pb.x = f2bf(v2.x) | (f2bf(v2.y) << 16);
        pb.y = f2bf(v2.z) | (f2bf(v2.w) << 16);
        pb.z = f2bf(v3.x) | (f2bf(v3.y) << 16);
        pb.w = f2bf(v3.z) | (f2bf(v3.w) << 16);
        *(uint4*)As_w0 = pa;
        *(uint4*)As_w1 = pb;
        __syncthreads();

#pragma unroll
        for (int s = 0; s < 2; ++s) {
            const int kq = s * 4 + q;
            bf16x8 a[2], b[2];
#pragma unroll
            for (int mi = 0; mi < 2; ++mi)
                a[mi] = *(const bf16x8*)&As[(((wm + mi * 16 + fm) << 3) + (kq ^ fm7)) << 3];
#pragma unroll
            for (int ni = 0; ni < 2; ++ni)
                b[ni] = *(const bf16x8*)&Bs[(((wn + ni * 16 + fm) << 3) + (kq ^ fm7)) << 3];
#pragma unroll
            for (int mi = 0; mi < 2; ++mi)
#pragma unroll
                for (int ni = 0; ni < 2; ++ni)
                    acc[mi][ni] = __builtin_amdgcn_mfma_f32_16x16x32_bf16(
                        a[mi], b[ni], acc[mi][ni], 0, 0, 0);
        }
        __syncthreads();
    }

    const int cm = (lane >> 4) * 4;   // C/D: col = lane&15, row = (lane>>4)*4 + reg
#pragma unroll
    for (int ni = 0; ni < 2; ++ni) {
        const int c = col0 + wn + ni * 16 + fm;
        const float bv = bias[c];
#pragma unroll
        for (int mi = 0; mi < 2; ++mi) {
#pragma unroll
            for (int r = 0; r < 4; ++r) {
                const int row = row0 + wm + mi * 16 + cm + r;
                H[(size_t)row * OUT_F + c] = (unsigned short)f2bf(acc[mi][ni][r] + bv);
            }
        }
    }
}

// ---- aggregate: wave-per-node. 64 lanes x 8 feats = 512. No block barriers. ----
__global__ __launch_bounds__(256) void aggregate(const unsigned short* __restrict__ H,
                                                 const int* __restrict__ dg,
                                                 const int* __restrict__ col,
                                                 float* __restrict__ out) {
    __shared__ int nbr[4][MAX_DEG];
    __shared__ int uniq[4][MAX_DEG];
    __shared__ int wcnt[4];
    const int wave = threadIdx.x >> 6;
    const int lane = threadIdx.x & 63;
    const int v    = blockIdx.x * 4 + wave;
    int d = dg[v];
    if (d > MAX_DEG) d = MAX_DEG;

    if (lane == 0) wcnt[wave] = 0;
    int id0 = -1, id1 = -1;
    if (lane < d)      { id0 = col[v * STRIDE + lane];      nbr[wave][lane]      = id0; }
    if (64 + lane < d) { id1 = col[v * STRIDE + 64 + lane]; nbr[wave][64 + lane] = id1; }
    __builtin_amdgcn_wave_barrier();

    bool k0 = (lane < d);
    const int lim0 = k0 ? lane : 0;
    for (int j = 0; j < lim0; ++j) k0 = k0 & (nbr[wave][j] != id0);
    bool k1 = (64 + lane < d);
    const int lim1 = k1 ? (64 + lane) : 0;
    for (int j = 0; j < lim1; ++j) k1 = k1 & (nbr[wave][j] != id1);
    if (k0) uniq[wave][atomicAdd(&wcnt[wave], 1)] = id0;
    if (k1) uniq[wave][atomicAdd(&wcnt[wave], 1)] = id1;
    __builtin_amdgcn_wave_barrier();
    const int n  = wcnt[wave];
    const int f0 = lane * 8;

    float a0=0,a1=0,a2=0,a3=0,a4=0,a5=0,a6=0,a7=0;
    int e = 0;
    for (; e + 4 <= n; e += 4) {
        const int i0 = uniq[wave][e], i1 = uniq[wave][e+1],
                  i2 = uniq[wave][e+2], i3 = uniq[wave][e+3];
        uint4 h0 = *(const uint4*)&H[(size_t)i0 * OUT_F + f0];
        uint4 h1 = *(const uint4*)&H[(size_t)i1 * OUT_F + f0];
        uint4 h2 = *(const uint4*)&H[(size_t)i2 * OUT_F + f0];
        uint4 h3 = *(const uint4*)&H[(size_t)i3 * OUT_F + f0];
        a0 += bflo(h0.x)+bflo(h1.x)+bflo(h2.x)+bflo(h3.x);
        a1 += bfhi(h0.x)+bfhi(h1.x)+bfhi(h2.x)+bfhi(h3.x);
        a2 += bflo(h0.y)+bflo(h1.y)+bflo(h2.y)+bflo(h3.y);
        a3 += bfhi(h0.y)+bfhi(h1.y)+bfhi(h2.y)+bfhi(h3.y);
        a4 += bflo(h0.z)+bflo(h1.z)+bflo(h2.z)+bflo(h3.z);
        a5 += bfhi(h0.z)+bfhi(h1.z)+bfhi(h2.z)+bfhi(h3.z);
        a6 += bflo(h0.w)+bflo(h1.w)+bflo(h2.w)+bflo(h3.w);
        a7 += bfhi(h0.w)+bfhi(h1.w)+bfhi(h2.w)+bfhi(h3.w);
    }
    for (; e < n; ++e) {
        uint4 h0 = *(const uint4*)&H[(size_t)uniq[wave][e] * OUT_F + f0];
        a0 += bflo(h0.x); a1 += bfhi(h0.x);
        a2 += bflo(h0.y); a3 += bfhi(h0.y);
        a4 += bflo(h0.z); a5 += bfhi(h0.z);
        a6 += bflo(h0.w); a7 += bfhi(h0.w);
    }
    f32x4 o0 = {fmaxf(a0,0.f), fmaxf(a1,0.f), fmaxf(a2,0.f), fmaxf(a3,0.f)};
    f32x4 o1 = {fmaxf(a4,0.f), fmaxf(a5,0.f), fmaxf(a6,0.f), fmaxf(a7,0.f)};
    __builtin_nontemporal_store(o0, (f32x4*)&out[(size_t)v * OUT_F + f0]);
    __builtin_nontemporal_store(o1, (f32x4*)&out[(size_t)v * OUT_F + f0 + 4]);
}

extern "C" void kernel_launch(void* const* d_in, const int* in_sizes, int n_in,
                              void* d_out, int out_size, void* d_ws, size_t ws_size,
                              hipStream_t stream) {
    const float* x  = (const float*)d_in[0];
    const float* W  = (const float*)d_in[1];
    const float* b  = (const float*)d_in[2];
    const int*   ei = (const int*)d_in[3];      // [2, N_EDGES]: src then dst
    float* out = (float*)d_out;

    char* ws = (char*)d_ws;
    unsigned short* H       = (unsigned short*)(ws + HID_OFF);
    unsigned short* Wb      = (unsigned short*)(ws + WB_OFF);
    int*            deg     = (int*)(ws + DEG_OFF);
    int*            col     = (int*)(ws + COL_OFF);
    int*            blkhist = (int*)(ws + BH_OFF);
    int*            boff    = (int*)(ws + BO_OFF);

    const int* src = ei;
    const int* dst = ei + N_EDGES;

    // 1) W cvt (256 blocks) + per-block histograms (64 blocks), fused
    prep_hist<<<256 + NBLK, 256, 0, stream>>>(W, Wb, src, blkhist);
    // 2) per-node prefix over block counts -> boff, deg
    scan_b<<<N_NODES / 256, 256, 0, stream>>>(blkhist, boff, deg);
    // 3) GEMM (1024 blocks) + place pass (64 blocks), fused
    gemm_place<<<1024 + NBLK, 256, 0, stream>>>(x, Wb, b, H, src, dst, boff, col);
    // 4) per-node dedup + gather + ReLU, one wave per node
    aggregate<<<N_NODES / 4, 256, 0, stream>>>(H, deg, col, out);
}

// Round 11
// 151.067 us; speedup vs baseline: 1.1175x; 1.0137x over previous
//
#include <hip/hip_runtime.h>
#include <hip/hip_bf16.h>

#define N_NODES 8192
#define IN_F    1024
#define OUT_F   512
#define N_EDGES 262144
#define STRIDE  96                // fixed adjacency row stride; P(deg>=96) ~ 1e-18
#define NBLK    64                // counting-sort blocks: 64 x 4096 edges
#define EPB     (N_EDGES / NBLK)  // 4096 edges per block

// ---------------- workspace layout (bytes) ----------------
#define HID_OFF     0u            // 8192*512*2 = 8,388,608  (bf16 H)
#define DEG_OFF     8388608u      // 8192*4 = 32,768
#define COL_OFF     8421376u      // 8192*96*4 = 3,145,728
#define BH_OFF      11567104u     // 64*8192*4 = 2,097,152   (blkhist)
#define BO_OFF      13664256u     // 64*8192*4 = 2,097,152   (boff) -> ends 15,761,408
#define MAX_DEG     STRIDE

typedef short  bf16x8 __attribute__((ext_vector_type(8)));
typedef float  f32x4  __attribute__((ext_vector_type(4)));

// lgkm-only barrier: LDS writes visible, global prefetch loads stay in flight
// (__syncthreads would emit s_waitcnt vmcnt(0) and kill the pipeline)
#define PIPE_BARRIER() __asm__ __volatile__("s_waitcnt lgkmcnt(0)\ns_barrier" ::: "memory")

__device__ __forceinline__ unsigned f2bf(float f) {
    unsigned u = __float_as_uint(f);
    u += 0x7fffu + ((u >> 16) & 1u);   // round-to-nearest-even
    return u >> 16;
}

__device__ __forceinline__ float bflo(unsigned u) { return __uint_as_float(u << 16); }
__device__ __forceinline__ float bfhi(unsigned u) { return __uint_as_float(u & 0xffff0000u); }

// fp32x4 -> 4 bf16 (RNE) via v_cvt_pk_bf16_f32, packed for ds_write_b64
__device__ __forceinline__ uint2 pkcvt(f32x4 v) {
    float2 p0 = {v.x, v.y}, p1 = {v.z, v.w};
    __hip_bfloat162 b0 = __float22bfloat162_rn(p0);
    __hip_bfloat162 b1 = __float22bfloat162_rn(p1);
    uint2 r;
    r.x = *(const unsigned*)&b0;
    r.y = *(const unsigned*)&b1;
    return r;
}

// --- hist: per-block LDS histogram of src over 8192 bins, no global atomics ---
__global__ __launch_bounds__(256) void hist(const int* __restrict__ src,
                                            int* __restrict__ blkhist) {
    __shared__ int h[N_NODES];            // 32 KB
    const int b   = blockIdx.x;
    const int tid = threadIdx.x;
    for (int i = tid; i < N_NODES; i += 256) h[i] = 0;
    __syncthreads();
    const int e0 = b * EPB;
#pragma unroll
    for (int j = 0; j < EPB / 256; ++j)
        atomicAdd(&h[src[e0 + j * 256 + tid]], 1);
    __syncthreads();
    for (int i = tid; i < N_NODES; i += 256)
        blkhist[b * N_NODES + i] = h[i];
}

// --- scanB: per node, prefix over 64 block counts -> local boff + deg ---
__global__ __launch_bounds__(256) void scan_b(const int* __restrict__ blkhist,
                                              int* __restrict__ boff,
                                              int* __restrict__ deg) {
    const int i = blockIdx.x * 256 + threadIdx.x;   // node id, grid 32x256 = 8192
    int s = 0;
#pragma unroll 8
    for (int b = 0; b < NBLK; ++b) {
        int t = blkhist[b * N_NODES + i];
        boff[b * N_NODES + i] = s;
        s += t;
    }
    deg[i] = s;
}

// ------ fused: pipelined MFMA GEMM (blocks 0..1023) + place (1024..1087) ------
// GEMM 64x64 tile, BK=64, dbuf LDS 2x(8+8) KB. Per iter: prefetch X/W fp32 for
// k+1 (coalesced lane-contiguous float4), MFMA on buf[cur], pkcvt+ds_write_b64
// into buf[1-cur], lgkm-only barrier (prefetch stays in flight -> latency hidden
// behind MFMA + other blocks). W converted inline: no cvt prepass at all.
// LDS chunk (row, c) at slot c^(row&7): frag ds_read_b128 2-way (free).
__global__ __launch_bounds__(256, 4) void gemm_place(const float* __restrict__ X,
                                                     const float* __restrict__ W,
                                                     const float* __restrict__ bias,
                                                     unsigned short* __restrict__ H,
                                                     const int* __restrict__ src,
                                                     const int* __restrict__ dst,
                                                     const int* __restrict__ boff,
                                                     int* __restrict__ col) {
    __shared__ int smem[N_NODES];            // 32 KB union
    const int bid = blockIdx.x;
    const int tid = threadIdx.x;

    if (bid >= 1024) {                       // ---- place pass ----
        const int b = bid - 1024;
        for (int i = tid; i < N_NODES; i += 256) smem[i] = 0;
        __syncthreads();
        const int e0 = b * EPB;
#pragma unroll
        for (int j = 0; j < EPB / 256; ++j) {
            int e = e0 + j * 256 + tid;
            int s = src[e];
            int r = boff[b * N_NODES + s] + atomicAdd(&smem[s], 1);
            if (r < STRIDE) col[s * STRIDE + r] = dst[e];
        }
        return;
    }

    // ---- pipelined GEMM ----
    unsigned short* As[2] = {(unsigned short*)smem,        (unsigned short*)smem + 8192};
    unsigned short* Bs[2] = {(unsigned short*)smem + 4096, (unsigned short*)smem + 12288};

    const int lane = tid & 63;
    const int wave = tid >> 6;
    const int row0 = (bid & 127) * 64;       // bid%8 groups row-tiles per XCD
    const int col0 = (bid >> 7) * 64;
    const int wm   = (wave & 1) * 32;
    const int wn   = (wave >> 1) * 32;
    const int fm   = lane & 15;
    const int fm7  = fm & 7;
    const int q    = lane >> 4;

    f32x4 acc[2][2];
#pragma unroll
    for (int i = 0; i < 2; ++i)
#pragma unroll
        for (int j = 0; j < 2; ++j) acc[i][j] = (f32x4)0.f;

    // staging: thread t covers 16B-unit u = t&15 of rows rr+16j (fully coalesced:
    // load j -> lanes contiguous over (row, u))
    const int u  = tid & 15;
    const int rr = tid >> 4;
    const float* gA = X + (size_t)(row0 + rr) * IN_F + 4 * u;
    const float* gB = W + (size_t)(col0 + rr) * IN_F + 4 * u;
    int lws[4];
#pragma unroll
    for (int j = 0; j < 4; ++j)     // ushort offset: row*64 + (c^(row&7))*8 + half*4
        lws[j] = (rr + 16 * j) * 64 + (((u >> 1) ^ (rr & 7)) * 8) + (u & 1) * 4;

    f32x4 va[4], vb[4];
#pragma unroll
    for (int j = 0; j < 4; ++j) {            // prologue: loads for k=0
        va[j] = *(const f32x4*)(gA + (size_t)j * 16 * IN_F);
        vb[j] = *(const f32x4*)(gB + (size_t)j * 16 * IN_F);
    }
#pragma unroll
    for (int j = 0; j < 4; ++j) {
        *(uint2*)(As[0] + lws[j]) = pkcvt(va[j]);
        *(uint2*)(Bs[0] + lws[j]) = pkcvt(vb[j]);
    }
    PIPE_BARRIER();

#pragma unroll
    for (int k = 0; k < IN_F / 64; ++k) {
        const int cur = k & 1;
        if (k + 1 < IN_F / 64) {             // issue prefetch (stays in flight)
            const float* pa = gA + (size_t)(k + 1) * 64;
            const float* pb = gB + (size_t)(k + 1) * 64;
#pragma unroll
            for (int j = 0; j < 4; ++j) {
                va[j] = *(const f32x4*)(pa + (size_t)j * 16 * IN_F);
                vb[j] = *(const f32x4*)(pb + (size_t)j * 16 * IN_F);
            }
        }
        unsigned short* Ac = As[cur];
        unsigned short* Bc = Bs[cur];
#pragma unroll
        for (int s = 0; s < 2; ++s) {        // two 32-k MFMA windows
            const int kq = s * 4 + q;
            bf16x8 a0 = *(const bf16x8*)&Ac[(((wm      + fm) << 3) + (kq ^ fm7)) << 3];
            bf16x8 a1 = *(const bf16x8*)&Ac[(((wm + 16 + fm) << 3) + (kq ^ fm7)) << 3];
            bf16x8 b0 = *(const bf16x8*)&Bc[(((wn      + fm) << 3) + (kq ^ fm7)) << 3];
            bf16x8 b1 = *(const bf16x8*)&Bc[(((wn + 16 + fm) << 3) + (kq ^ fm7)) << 3];
            acc[0][0] = __builtin_amdgcn_mfma_f32_16x16x32_bf16(a0, b0, acc[0][0], 0, 0, 0);
            acc[0][1] = __builtin_amdgcn_mfma_f32_16x16x32_bf16(a0, b1, acc[0][1], 0, 0, 0);
            acc[1][0] = __builtin_amdgcn_mfma_f32_16x16x32_bf16(a1, b0, acc[1][0], 0, 0, 0);
            acc[1][1] = __builtin_amdgcn_mfma_f32_16x16x32_bf16(a1, b1, acc[1][1], 0, 0, 0);
        }
        if (k + 1 < IN_F / 64) {             // pack prefetch into other buffer
            unsigned short* An = As[1 - cur];
            unsigned short* Bn = Bs[1 - cur];
#pragma unroll
            for (int j = 0; j < 4; ++j) {
                *(uint2*)(An + lws[j]) = pkcvt(va[j]);
                *(uint2*)(Bn + lws[j]) = pkcvt(vb[j]);
            }
            PIPE_BARRIER();
        }
    }

    const int cm = (lane >> 4) * 4;   // C/D: col = lane&15, row = (lane>>4)*4 + reg
#pragma unroll
    for (int ni = 0; ni < 2; ++ni) {
        const int c = col0 + wn + ni * 16 + fm;
        const float bv = bias[c];
#pragma unroll
        for (int mi = 0; mi < 2; ++mi) {
#pragma unroll
            for (int r = 0; r < 4; ++r) {
                const int row = row0 + wm + mi * 16 + cm + r;
                H[(size_t)row * OUT_F + c] = (unsigned short)f2bf(acc[mi][ni][r] + bv);
            }
        }
    }
}

// ---- aggregate: wave-per-node. 64 lanes x 8 feats = 512. No block barriers. ----
__global__ __launch_bounds__(256) void aggregate(const unsigned short* __restrict__ H,
                                                 const int* __restrict__ dg,
                                                 const int* __restrict__ col,
                                                 float* __restrict__ out) {
    __shared__ int nbr[4][MAX_DEG];
    __shared__ int uniq[4][MAX_DEG];
    __shared__ int wcnt[4];
    const int wave = threadIdx.x >> 6;
    const int lane = threadIdx.x & 63;
    const int v    = blockIdx.x * 4 + wave;
    int d = dg[v];
    if (d > MAX_DEG) d = MAX_DEG;

    if (lane == 0) wcnt[wave] = 0;
    int id0 = -1, id1 = -1;
    if (lane < d)      { id0 = col[v * STRIDE + lane];      nbr[wave][lane]      = id0; }
    if (64 + lane < d) { id1 = col[v * STRIDE + 64 + lane]; nbr[wave][64 + lane] = id1; }
    __builtin_amdgcn_wave_barrier();

    bool k0 = (lane < d);
    const int lim0 = k0 ? lane : 0;
    for (int j = 0; j < lim0; ++j) k0 = k0 & (nbr[wave][j] != id0);
    bool k1 = (64 + lane < d);
    const int lim1 = k1 ? (64 + lane) : 0;
    for (int j = 0; j < lim1; ++j) k1 = k1 & (nbr[wave][j] != id1);
    if (k0) uniq[wave][atomicAdd(&wcnt[wave], 1)] = id0;
    if (k1) uniq[wave][atomicAdd(&wcnt[wave], 1)] = id1;
    __builtin_amdgcn_wave_barrier();
    const int n  = wcnt[wave];
    const int f0 = lane * 8;

    float a0=0,a1=0,a2=0,a3=0,a4=0,a5=0,a6=0,a7=0;
    int e = 0;
    for (; e + 4 <= n; e += 4) {
        const int i0 = uniq[wave][e], i1 = uniq[wave][e+1],
                  i2 = uniq[wave][e+2], i3 = uniq[wave][e+3];
        uint4 h0 = *(const uint4*)&H[(size_t)i0 * OUT_F + f0];
        uint4 h1 = *(const uint4*)&H[(size_t)i1 * OUT_F + f0];
        uint4 h2 = *(const uint4*)&H[(size_t)i2 * OUT_F + f0];
        uint4 h3 = *(const uint4*)&H[(size_t)i3 * OUT_F + f0];
        a0 += bflo(h0.x)+bflo(h1.x)+bflo(h2.x)+bflo(h3.x);
        a1 += bfhi(h0.x)+bfhi(h1.x)+bfhi(h2.x)+bfhi(h3.x);
        a2 += bflo(h0.y)+bflo(h1.y)+bflo(h2.y)+bflo(h3.y);
        a3 += bfhi(h0.y)+bfhi(h1.y)+bfhi(h2.y)+bfhi(h3.y);
        a4 += bflo(h0.z)+bflo(h1.z)+bflo(h2.z)+bflo(h3.z);
        a5 += bfhi(h0.z)+bfhi(h1.z)+bfhi(h2.z)+bfhi(h3.z);
        a6 += bflo(h0.w)+bflo(h1.w)+bflo(h2.w)+bflo(h3.w);
        a7 += bfhi(h0.w)+bfhi(h1.w)+bfhi(h2.w)+bfhi(h3.w);
    }
    for (; e < n; ++e) {
        uint4 h0 = *(const uint4*)&H[(size_t)uniq[wave][e] * OUT_F + f0];
        a0 += bflo(h0.x); a1 += bfhi(h0.x);
        a2 += bflo(h0.y); a3 += bfhi(h0.y);
        a4 += bflo(h0.z); a5 += bfhi(h0.z);
        a6 += bflo(h0.w); a7 += bfhi(h0.w);
    }
    f32x4 o0 = {fmaxf(a0,0.f), fmaxf(a1,0.f), fmaxf(a2,0.f), fmaxf(a3,0.f)};
    f32x4 o1 = {fmaxf(a4,0.f), fmaxf(a5,0.f), fmaxf(a6,0.f), fmaxf(a7,0.f)};
    __builtin_nontemporal_store(o0, (f32x4*)&out[(size_t)v * OUT_F + f0]);
    __builtin_nontemporal_store(o1, (f32x4*)&out[(size_t)v * OUT_F + f0 + 4]);
}

extern "C" void kernel_launch(void* const* d_in, const int* in_sizes, int n_in,
                              void* d_out, int out_size, void* d_ws, size_t ws_size,
                              hipStream_t stream) {
    const float* x  = (const float*)d_in[0];
    const float* W  = (const float*)d_in[1];
    const float* b  = (const float*)d_in[2];
    const int*   ei = (const int*)d_in[3];      // [2, N_EDGES]: src then dst
    float* out = (float*)d_out;

    char* ws = (char*)d_ws;
    unsigned short* H       = (unsigned short*)(ws + HID_OFF);
    int*            deg     = (int*)(ws + DEG_OFF);
    int*            col     = (int*)(ws + COL_OFF);
    int*            blkhist = (int*)(ws + BH_OFF);
    int*            boff    = (int*)(ws + BO_OFF);

    const int* src = ei;
    const int* dst = ei + N_EDGES;

    // 1) per-block src histograms (no global atomics)
    hist<<<NBLK, 256, 0, stream>>>(src, blkhist);
    // 2) per-node prefix over block counts -> boff, deg
    scan_b<<<N_NODES / 256, 256, 0, stream>>>(blkhist, boff, deg);
    // 3) pipelined GEMM w/ inline fp32->bf16 (1024 blocks) + place (64 blocks)
    gemm_place<<<1024 + NBLK, 256, 0, stream>>>(x, W, b, H, src, dst, boff, col);
    // 4) per-node dedup + gather + ReLU, one wave per node
    aggregate<<<N_NODES / 4, 256, 0, stream>>>(H, deg, col, out);
}

// Round 12
// 144.860 us; speedup vs baseline: 1.1654x; 1.0429x over previous
//
#include <hip/hip_runtime.h>

#define N_NODES 8192
#define IN_F    1024
#define OUT_F   512
#define N_EDGES 262144
#define STRIDE  96                // fixed adjacency row stride; P(deg>=96) ~ 1e-18

// ---------------- workspace layout (bytes) ----------------
#define HID_OFF     0u            // 8192*512*2   =  8,388,608  (bf16 H)
#define XB_OFF      8388608u      // 8192*1024*2  = 16,777,216  (bf16 X)
#define WB_OFF      25165824u     // 512*1024*2   =  1,048,576  (bf16 W, contiguous after Xb)
#define DEG_OFF     26214400u     // 8192*4 = 32,768
#define COL_OFF     26247168u     // 8192*96*4 = 3,145,728 -> ends 29,392,896 (proven size)
#define MAX_DEG     STRIDE

typedef short  bf16x8 __attribute__((ext_vector_type(8)));
typedef float  f32x4  __attribute__((ext_vector_type(4)));

__device__ __forceinline__ unsigned f2bf(float f) {
    unsigned u = __float_as_uint(f);
    u += 0x7fffu + ((u >> 16) & 1u);   // round-to-nearest-even
    return u >> 16;
}

__device__ __forceinline__ float bflo(unsigned u) { return __uint_as_float(u << 16); }
__device__ __forceinline__ float bfhi(unsigned u) { return __uint_as_float(u & 0xffff0000u); }

__device__ __forceinline__ void ld_lds16(const void* g, void* l) {
    __builtin_amdgcn_global_load_lds(
        (const __attribute__((address_space(1))) void*)g,
        (__attribute__((address_space(3))) void*)l, 16, 0, 0);
}

// --- cvt: X and W fp32 -> bf16 (Xb,Wb contiguous); first 8192 threads zero deg ---
#define NX8 (N_NODES * IN_F / 8)          // 1,048,576 chunks of 8
#define NW8 (OUT_F * IN_F / 8)            //    65,536
__global__ __launch_bounds__(256) void cvt_all(const float* __restrict__ x,
                                               const float* __restrict__ w,
                                               unsigned short* __restrict__ xb,
                                               int* __restrict__ deg) {
    int i = blockIdx.x * blockDim.x + threadIdx.x;   // grid covers NX8+NW8 exactly
    if (i < N_NODES) deg[i] = 0;
    const f32x4* p = (i < NX8) ? ((const f32x4*)x + (size_t)i * 2)
                               : ((const f32x4*)w + (size_t)(i - NX8) * 2);
    f32x4 v0 = __builtin_nontemporal_load(p);        // fp32 inputs never re-read
    f32x4 v1 = __builtin_nontemporal_load(p + 1);
    uint4 o;
    o.x = f2bf(v0.x) | (f2bf(v0.y) << 16);
    o.y = f2bf(v0.z) | (f2bf(v0.w) << 16);
    o.z = f2bf(v1.x) | (f2bf(v1.y) << 16);
    o.w = f2bf(v1.z) | (f2bf(v1.w) << 16);
    *((uint4*)xb + i) = o;
}

// ------- fused: 128x128 MFMA GEMM (blocks 0..255) + edge scatter (256..1279) ----
// GEMM: 128x128 tile, BK=32 (32 iters), 4 waves (2x2), each wave 4x4 of 16x16x32.
// Logical L2 traffic: A 16.8MB x4 + B 1MB x64 = 131 MB (4x less than 64x64 tiles
// -- the R5..R11 GEMMs' hidden limiter). Tile->XCD grouping: bid%8 = rowtile%8,
// so each XCD re-reads a 2.1 MB X slice + 1 MB W from its own L2.
// Scatter: one contended atomicAdd pass, hidden behind the GEMM (R8-verified).
__global__ __launch_bounds__(256, 4) void gemm_scatter(const unsigned short* __restrict__ Xb,
                                                       const unsigned short* __restrict__ Wb,
                                                       const float* __restrict__ bias,
                                                       unsigned short* __restrict__ H,
                                                       const int* __restrict__ src,
                                                       const int* __restrict__ dst,
                                                       int* __restrict__ deg,
                                                       int* __restrict__ col) {
    __shared__ unsigned short As[128 * 32];   // 8 KB, [row][k] row-major
    __shared__ unsigned short Bs[128 * 32];   // 8 KB

    const int bid = blockIdx.x;
    const int tid = threadIdx.x;

    if (bid >= 256) {                        // ---- scatter part ----
        int e = (bid - 256) * 256 + tid;     // 1024*256 == N_EDGES exactly
        int s = src[e];
        int slot = atomicAdd(&deg[s], 1);
        if (slot < STRIDE) col[s * STRIDE + slot] = dst[e];
        return;
    }

    // ---- GEMM part (R2 structure, ref-verified) ----
    const int lane = tid & 63;
    const int wave = tid >> 6;
    const int row0 = (bid & 63) * 128;       // 64 row-tiles; bid%8 groups per XCD
    const int col0 = (bid >> 6) * 128;       // 4 col-tiles
    const int wm   = (wave & 1) * 64;
    const int wn   = (wave >> 1) * 64;
    const int fm   = lane & 15;
    const int fk   = (lane >> 4) * 8;

    f32x4 acc[4][4];
#pragma unroll
    for (int i = 0; i < 4; ++i)
#pragma unroll
        for (int j = 0; j < 4; ++j) acc[i][j] = (f32x4)0.f;

    const int r0 = tid >> 2, kc0 = (tid & 3) * 8;
    const int r1 = r0 + 64;

    for (int k0 = 0; k0 < IN_F; k0 += 32) {
        ld_lds16(Xb + (size_t)(row0 + r0) * IN_F + k0 + kc0, As + tid * 8);
        ld_lds16(Wb + (size_t)(col0 + r0) * IN_F + k0 + kc0, Bs + tid * 8);
        ld_lds16(Xb + (size_t)(row0 + r1) * IN_F + k0 + kc0, As + (tid + 256) * 8);
        ld_lds16(Wb + (size_t)(col0 + r1) * IN_F + k0 + kc0, Bs + (tid + 256) * 8);
        __syncthreads();

        bf16x8 a[4], b[4];
#pragma unroll
        for (int mi = 0; mi < 4; ++mi)
            a[mi] = *(const bf16x8*)&As[(wm + mi * 16 + fm) * 32 + fk];
#pragma unroll
        for (int ni = 0; ni < 4; ++ni)
            b[ni] = *(const bf16x8*)&Bs[(wn + ni * 16 + fm) * 32 + fk];
#pragma unroll
        for (int mi = 0; mi < 4; ++mi)
#pragma unroll
            for (int ni = 0; ni < 4; ++ni)
                acc[mi][ni] = __builtin_amdgcn_mfma_f32_16x16x32_bf16(
                    a[mi], b[ni], acc[mi][ni], 0, 0, 0);
        __syncthreads();
    }

    const int cm = (lane >> 4) * 4;   // C/D: col = lane&15, row = (lane>>4)*4 + reg
#pragma unroll
    for (int ni = 0; ni < 4; ++ni) {
        const int c = col0 + wn + ni * 16 + fm;
        const float bv = bias[c];
#pragma unroll
        for (int mi = 0; mi < 4; ++mi) {
#pragma unroll
            for (int r = 0; r < 4; ++r) {
                const int row = row0 + wm + mi * 16 + cm + r;
                H[(size_t)row * OUT_F + c] = (unsigned short)f2bf(acc[mi][ni][r] + bv);
            }
        }
    }
}

// ---- aggregate: wave-per-node. 64 lanes x 8 feats = 512. No block barriers. ----
__global__ __launch_bounds__(256) void aggregate(const unsigned short* __restrict__ H,
                                                 const int* __restrict__ dg,
                                                 const int* __restrict__ col,
                                                 float* __restrict__ out) {
    __shared__ int nbr[4][MAX_DEG];
    __shared__ int uniq[4][MAX_DEG];
    __shared__ int wcnt[4];
    const int wave = threadIdx.x >> 6;
    const int lane = threadIdx.x & 63;
    const int v    = blockIdx.x * 4 + wave;
    int d = dg[v];
    if (d > MAX_DEG) d = MAX_DEG;

    if (lane == 0) wcnt[wave] = 0;
    int id0 = -1, id1 = -1;
    if (lane < d)      { id0 = col[v * STRIDE + lane];      nbr[wave][lane]      = id0; }
    if (64 + lane < d) { id1 = col[v * STRIDE + 64 + lane]; nbr[wave][64 + lane] = id1; }
    __builtin_amdgcn_wave_barrier();

    bool k0 = (lane < d);
    const int lim0 = k0 ? lane : 0;
    for (int j = 0; j < lim0; ++j) k0 = k0 & (nbr[wave][j] != id0);
    bool k1 = (64 + lane < d);
    const int lim1 = k1 ? (64 + lane) : 0;
    for (int j = 0; j < lim1; ++j) k1 = k1 & (nbr[wave][j] != id1);
    if (k0) uniq[wave][atomicAdd(&wcnt[wave], 1)] = id0;
    if (k1) uniq[wave][atomicAdd(&wcnt[wave], 1)] = id1;
    __builtin_amdgcn_wave_barrier();
    const int n  = wcnt[wave];
    const int f0 = lane * 8;

    float a0=0,a1=0,a2=0,a3=0,a4=0,a5=0,a6=0,a7=0;
    int e = 0;
    for (; e + 4 <= n; e += 4) {
        const int i0 = uniq[wave][e], i1 = uniq[wave][e+1],
                  i2 = uniq[wave][e+2], i3 = uniq[wave][e+3];
        uint4 h0 = *(const uint4*)&H[(size_t)i0 * OUT_F + f0];
        uint4 h1 = *(const uint4*)&H[(size_t)i1 * OUT_F + f0];
        uint4 h2 = *(const uint4*)&H[(size_t)i2 * OUT_F + f0];
        uint4 h3 = *(const uint4*)&H[(size_t)i3 * OUT_F + f0];
        a0 += bflo(h0.x)+bflo(h1.x)+bflo(h2.x)+bflo(h3.x);
        a1 += bfhi(h0.x)+bfhi(h1.x)+bfhi(h2.x)+bfhi(h3.x);
        a2 += bflo(h0.y)+bflo(h1.y)+bflo(h2.y)+bflo(h3.y);
        a3 += bfhi(h0.y)+bfhi(h1.y)+bfhi(h2.y)+bfhi(h3.y);
        a4 += bflo(h0.z)+bflo(h1.z)+bflo(h2.z)+bflo(h3.z);
        a5 += bfhi(h0.z)+bfhi(h1.z)+bfhi(h2.z)+bfhi(h3.z);
        a6 += bflo(h0.w)+bflo(h1.w)+bflo(h2.w)+bflo(h3.w);
        a7 += bfhi(h0.w)+bfhi(h1.w)+bfhi(h2.w)+bfhi(h3.w);
    }
    for (; e < n; ++e) {
        uint4 h0 = *(const uint4*)&H[(size_t)uniq[wave][e] * OUT_F + f0];
        a0 += bflo(h0.x); a1 += bfhi(h0.x);
        a2 += bflo(h0.y); a3 += bfhi(h0.y);
        a4 += bflo(h0.z); a5 += bfhi(h0.z);
        a6 += bflo(h0.w); a7 += bfhi(h0.w);
    }
    f32x4 o0 = {fmaxf(a0,0.f), fmaxf(a1,0.f), fmaxf(a2,0.f), fmaxf(a3,0.f)};
    f32x4 o1 = {fmaxf(a4,0.f), fmaxf(a5,0.f), fmaxf(a6,0.f), fmaxf(a7,0.f)};
    __builtin_nontemporal_store(o0, (f32x4*)&out[(size_t)v * OUT_F + f0]);
    __builtin_nontemporal_store(o1, (f32x4*)&out[(size_t)v * OUT_F + f0 + 4]);
}

extern "C" void kernel_launch(void* const* d_in, const int* in_sizes, int n_in,
                              void* d_out, int out_size, void* d_ws, size_t ws_size,
                              hipStream_t stream) {
    const float* x  = (const float*)d_in[0];
    const float* W  = (const float*)d_in[1];
    const float* b  = (const float*)d_in[2];
    const int*   ei = (const int*)d_in[3];      // [2, N_EDGES]: src then dst
    float* out = (float*)d_out;

    char* ws = (char*)d_ws;
    unsigned short* H   = (unsigned short*)(ws + HID_OFF);
    unsigned short* Xb  = (unsigned short*)(ws + XB_OFF);   // Wb contiguous after
    int*            deg = (int*)(ws + DEG_OFF);
    int*            col = (int*)(ws + COL_OFF);

    // 1) X,W -> bf16 + zero deg (one pass, HBM-bound ~10 us)
    cvt_all<<<(NX8 + NW8) / 256, 256, 0, stream>>>(x, W, Xb, deg);

    // 2) 128x128 GEMM (256 blocks) + atomic edge scatter (1024 blocks), fused
    gemm_scatter<<<256 + 1024, 256, 0, stream>>>(Xb, (unsigned short*)(ws + WB_OFF),
                                                 b, H, ei, ei + N_EDGES, deg, col);

    // 3) per-node dedup + gather + ReLU, one wave per node
    aggregate<<<N_NODES / 4, 256, 0, stream>>>(H, deg, col, out);
}